// Round 1
// baseline (4058.658 us; speedup 1.0000x reference)
//
#include <hip/hip_runtime.h>
#include <hip/hip_bf16.h>

#define D_HID 256

// ---------------- degree via atomics ----------------
__global__ void deg_kernel(const int* __restrict__ dst, float* __restrict__ deg, int E) {
    int e = blockIdx.x * blockDim.x + threadIdx.x;
    if (e < E) atomicAdd(&deg[dst[e]], 1.0f);
}

__global__ void dinv_kernel(float* __restrict__ deg, int N) {
    int n = blockIdx.x * blockDim.x + threadIdx.x;
    if (n < N) deg[n] = rsqrtf(deg[n] + 1.0f);
}

// ---------------- embedding: h = x @ W_emb + b_emb  (K=10) ----------------
__global__ __launch_bounds__(256) void emb_kernel(const float* __restrict__ x,
                                                  const float* __restrict__ W,
                                                  const float* __restrict__ b,
                                                  float* __restrict__ h, int N) {
    int n = blockIdx.x;
    __shared__ float xs[10];
    if (threadIdx.x < 10) xs[threadIdx.x] = x[n * 10 + threadIdx.x];
    __syncthreads();
    int d = threadIdx.x;
    float s = b[d];
#pragma unroll
    for (int k = 0; k < 10; ++k) s += xs[k] * W[k * D_HID + d];
    h[(size_t)n * D_HID + d] = s;
}

// ---------------- fp32 tiled GEMM: C[M,256] = A[M,256] @ B[256,256] ----------------
#define BM 64
#define BN 64
#define BK 16
__global__ __launch_bounds__(256) void gemm_fp32(const float* __restrict__ A,
                                                 const float* __restrict__ B,
                                                 float* __restrict__ C, int M) {
    const int K = 256, N = 256;
    __shared__ float As[BK][BM + 1];
    __shared__ float Bs[BK][BN];
    int bm = blockIdx.x * BM;
    int bn = blockIdx.y * BN;
    int tid = threadIdx.x;
    int tx = tid & 15, ty = tid >> 4;
    float acc[4][4] = {};

    for (int k0 = 0; k0 < K; k0 += BK) {
        {   // A tile: 64 rows x 16 cols, one float4 per thread
            int row = tid >> 2, cg = tid & 3;
            int grow = bm + row;
            float4 v = make_float4(0.f, 0.f, 0.f, 0.f);
            if (grow < M) v = *(const float4*)&A[(size_t)grow * K + k0 + cg * 4];
            As[cg * 4 + 0][row] = v.x;
            As[cg * 4 + 1][row] = v.y;
            As[cg * 4 + 2][row] = v.z;
            As[cg * 4 + 3][row] = v.w;
        }
        {   // B tile: 16 rows x 64 cols
            int row = tid >> 4, cg = tid & 15;
            float4 v = *(const float4*)&B[(size_t)(k0 + row) * N + bn + cg * 4];
            *(float4*)&Bs[row][cg * 4] = v;
        }
        __syncthreads();
#pragma unroll
        for (int k = 0; k < BK; ++k) {
            float a[4], b[4];
#pragma unroll
            for (int i = 0; i < 4; ++i) a[i] = As[k][ty * 4 + i];
#pragma unroll
            for (int j = 0; j < 4; ++j) b[j] = Bs[k][tx * 4 + j];
#pragma unroll
            for (int i = 0; i < 4; ++i)
#pragma unroll
                for (int j = 0; j < 4; ++j) acc[i][j] += a[i] * b[j];
        }
        __syncthreads();
    }
#pragma unroll
    for (int i = 0; i < 4; ++i) {
        int grow = bm + ty * 4 + i;
        if (grow < M) {
            float4 v = make_float4(acc[i][0], acc[i][1], acc[i][2], acc[i][3]);
            *(float4*)&C[(size_t)grow * N + bn + tx * 4] = v;
        }
    }
}

// ---------------- scatter: agg[dst] += hw[src] * dinv[src]*dinv[dst] ----------------
__global__ __launch_bounds__(256) void scatter_kernel(const int* __restrict__ src,
                                                      const int* __restrict__ dst,
                                                      const float* __restrict__ dinv,
                                                      const float* __restrict__ hw,
                                                      float* __restrict__ agg, int E) {
    int wave = threadIdx.x >> 6;
    int lane = threadIdx.x & 63;
    int e = blockIdx.x * 4 + wave;
    if (e >= E) return;
    int s = src[e], t = dst[e];
    float norm = dinv[s] * dinv[t];
    float4 v = *(const float4*)&hw[(size_t)s * D_HID + lane * 4];
    float* p = &agg[(size_t)t * D_HID + lane * 4];
    atomicAdd(p + 0, v.x * norm);
    atomicAdd(p + 1, v.y * norm);
    atomicAdd(p + 2, v.z * norm);
    atomicAdd(p + 3, v.w * norm);
}

// ---------------- combine: h = relu(agg + hw*dinv^2 + b) + h ----------------
__global__ __launch_bounds__(256) void combine_kernel(const float* __restrict__ agg,
                                                      const float* __restrict__ hw,
                                                      const float* __restrict__ dinv,
                                                      const float* __restrict__ b,
                                                      float* __restrict__ h, int total4) {
    int idx = blockIdx.x * blockDim.x + threadIdx.x;
    if (idx >= total4) return;
    size_t i4 = (size_t)idx * 4;
    int n = (int)(i4 >> 8);
    int d = (int)(i4 & 255);
    float di = dinv[n];
    float sl = di * di;
    float4 a = *(const float4*)&agg[i4];
    float4 w = *(const float4*)&hw[i4];
    float4 hv = *(const float4*)&h[i4];
    float4 bb = *(const float4*)&b[d];
    float4 r;
    r.x = fmaxf(a.x + w.x * sl + bb.x, 0.f) + hv.x;
    r.y = fmaxf(a.y + w.y * sl + bb.y, 0.f) + hv.y;
    r.z = fmaxf(a.z + w.z * sl + bb.z, 0.f) + hv.z;
    r.w = fmaxf(a.w + w.w * sl + bb.w, 0.f) + hv.w;
    *(float4*)&h[i4] = r;
}

extern "C" void kernel_launch(void* const* d_in, const int* in_sizes, int n_in,
                              void* d_out, int out_size, void* d_ws, size_t ws_size,
                              hipStream_t stream) {
    const float* x     = (const float*)d_in[0];
    const int*   edge  = (const int*)d_in[1];
    const float* W_emb = (const float*)d_in[2];
    const float* b_emb = (const float*)d_in[3];
    const float* W[3]  = {(const float*)d_in[4], (const float*)d_in[6], (const float*)d_in[8]};
    const float* B[3]  = {(const float*)d_in[5], (const float*)d_in[7], (const float*)d_in[9]};

    int N = in_sizes[0] / 10;     // 100000
    int E = in_sizes[1] / 2;      // 320000
    size_t NH = (size_t)N * D_HID;  // 25.6M elements

    float* h   = (float*)d_out;
    float* hw  = (float*)d_ws;
    float* agg = hw + NH;
    float* deg = agg + NH;        // reused in-place as dinv

    const int* src = edge;
    const int* dst = edge + E;

    // degree + dinv (layer-invariant)
    hipMemsetAsync(deg, 0, (size_t)N * sizeof(float), stream);
    deg_kernel<<<(E + 255) / 256, 256, 0, stream>>>(dst, deg, E);
    dinv_kernel<<<(N + 255) / 256, 256, 0, stream>>>(deg, N);

    // embedding
    emb_kernel<<<N, 256, 0, stream>>>(x, W_emb, b_emb, h, N);

    int total4 = (int)(NH / 4);
    dim3 ggrid((N + BM - 1) / BM, D_HID / BN);
    for (int l = 0; l < 3; ++l) {
        gemm_fp32<<<ggrid, 256, 0, stream>>>(h, W[l], hw, N);
        hipMemsetAsync(agg, 0, NH * sizeof(float), stream);
        scatter_kernel<<<(E + 3) / 4, 256, 0, stream>>>(src, dst, deg, hw, agg, E);
        combine_kernel<<<(total4 + 255) / 256, 256, 0, stream>>>(agg, hw, deg, B[l], h, total4);
    }
}

// Round 2
// 926.890 us; speedup vs baseline: 4.3788x; 4.3788x over previous
//
#include <hip/hip_runtime.h>
#include <hip/hip_bf16.h>

#define D_HID 256

// ---------------- degree count (int atomics, 320k ops) ----------------
__global__ void deg_kernel(const int* __restrict__ dst, int* __restrict__ degi, int E) {
    int e = blockIdx.x * blockDim.x + threadIdx.x;
    if (e < E) atomicAdd(&degi[dst[e]], 1);
}

__global__ void dinv_kernel(const int* __restrict__ degi, float* __restrict__ dinv, int N) {
    int n = blockIdx.x * blockDim.x + threadIdx.x;
    if (n < N) dinv[n] = rsqrtf((float)degi[n] + 1.0f);
}

// ---------------- exclusive scan of degi -> row_off (3-kernel) ----------------
__global__ __launch_bounds__(256) void scanA(const int* __restrict__ degi,
                                             int* __restrict__ row_off,
                                             int* __restrict__ partials, int N) {
    __shared__ int sdata[256];
    int tid = threadIdx.x;
    int base = blockIdx.x * 1024 + tid * 4;
    int s[4];
#pragma unroll
    for (int j = 0; j < 4; ++j) s[j] = (base + j < N) ? degi[base + j] : 0;
    int t = s[0] + s[1] + s[2] + s[3];
    sdata[tid] = t;
    __syncthreads();
    for (int ofs = 1; ofs < 256; ofs <<= 1) {
        int v = (tid >= ofs) ? sdata[tid - ofs] : 0;
        __syncthreads();
        sdata[tid] += v;
        __syncthreads();
    }
    int excl = sdata[tid] - t;
    int run = excl;
#pragma unroll
    for (int j = 0; j < 4; ++j) {
        if (base + j < N) row_off[base + j] = run;
        run += s[j];
    }
    if (tid == 255) partials[blockIdx.x] = sdata[255];
}

__global__ void scanB(int* __restrict__ partials, int nb) {
    if (threadIdx.x == 0 && blockIdx.x == 0) {
        int run = 0;
        for (int i = 0; i < nb; ++i) { int t = partials[i]; partials[i] = run; run += t; }
    }
}

__global__ __launch_bounds__(256) void scanC(int* __restrict__ row_off,
                                             const int* __restrict__ partials, int N) {
    int add = partials[blockIdx.x];
    int base = blockIdx.x * 1024 + threadIdx.x * 4;
#pragma unroll
    for (int j = 0; j < 4; ++j)
        if (base + j < N) row_off[base + j] += add;
}

// ---------------- CSR fill: csr[pos] = {src, norm} ----------------
__global__ void fill_kernel(const int* __restrict__ src, const int* __restrict__ dst,
                            const int* __restrict__ row_off, int* __restrict__ cursor,
                            const float* __restrict__ dinv, int2* __restrict__ csr, int E) {
    int e = blockIdx.x * blockDim.x + threadIdx.x;
    if (e >= E) return;
    int s = src[e], t = dst[e];
    int pos = row_off[t] + atomicAdd(&cursor[t], 1);
    csr[pos] = make_int2(s, __float_as_int(dinv[s] * dinv[t]));
}

// ---------------- embedding: h = x @ W_emb + b_emb  (K=10) ----------------
__global__ __launch_bounds__(256) void emb_kernel(const float* __restrict__ x,
                                                  const float* __restrict__ W,
                                                  const float* __restrict__ b,
                                                  float* __restrict__ h, int N) {
    int n = blockIdx.x;
    __shared__ float xs[10];
    if (threadIdx.x < 10) xs[threadIdx.x] = x[n * 10 + threadIdx.x];
    __syncthreads();
    int d = threadIdx.x;
    float s = b[d];
#pragma unroll
    for (int k = 0; k < 10; ++k) s += xs[k] * W[k * D_HID + d];
    h[(size_t)n * D_HID + d] = s;
}

// ---------------- fp32 tiled GEMM: C[M,256] = A[M,256] @ B[256,256] ----------------
#define BM 64
#define BN 64
#define BK 16
__global__ __launch_bounds__(256) void gemm_fp32(const float* __restrict__ A,
                                                 const float* __restrict__ B,
                                                 float* __restrict__ C, int M) {
    const int K = 256, N = 256;
    __shared__ float As[BK][BM + 1];
    __shared__ float Bs[BK][BN];
    int bm = blockIdx.x * BM;
    int bn = blockIdx.y * BN;
    int tid = threadIdx.x;
    int tx = tid & 15, ty = tid >> 4;
    float acc[4][4] = {};

    for (int k0 = 0; k0 < K; k0 += BK) {
        {
            int row = tid >> 2, cg = tid & 3;
            int grow = bm + row;
            float4 v = make_float4(0.f, 0.f, 0.f, 0.f);
            if (grow < M) v = *(const float4*)&A[(size_t)grow * K + k0 + cg * 4];
            As[cg * 4 + 0][row] = v.x;
            As[cg * 4 + 1][row] = v.y;
            As[cg * 4 + 2][row] = v.z;
            As[cg * 4 + 3][row] = v.w;
        }
        {
            int row = tid >> 4, cg = tid & 15;
            float4 v = *(const float4*)&B[(size_t)(k0 + row) * N + bn + cg * 4];
            *(float4*)&Bs[row][cg * 4] = v;
        }
        __syncthreads();
#pragma unroll
        for (int k = 0; k < BK; ++k) {
            float a[4], b[4];
#pragma unroll
            for (int i = 0; i < 4; ++i) a[i] = As[k][ty * 4 + i];
#pragma unroll
            for (int j = 0; j < 4; ++j) b[j] = Bs[k][tx * 4 + j];
#pragma unroll
            for (int i = 0; i < 4; ++i)
#pragma unroll
                for (int j = 0; j < 4; ++j) acc[i][j] += a[i] * b[j];
        }
        __syncthreads();
    }
#pragma unroll
    for (int i = 0; i < 4; ++i) {
        int grow = bm + ty * 4 + i;
        if (grow < M) {
            float4 v = make_float4(acc[i][0], acc[i][1], acc[i][2], acc[i][3]);
            *(float4*)&C[(size_t)grow * N + bn + tx * 4] = v;
        }
    }
}

// ---------------- fused gather-aggregate + combine ----------------
// one wave per node: acc = sum_{e in dst==n} hw[src_e]*norm_e
// h[n] = relu(acc + hw[n]*dinv[n]^2 + b) + h[n]
__global__ __launch_bounds__(256) void agg_combine(const int* __restrict__ row_off,
                                                   const int* __restrict__ degi,
                                                   const int2* __restrict__ csr,
                                                   const float* __restrict__ hw,
                                                   const float* __restrict__ dinv,
                                                   const float* __restrict__ b,
                                                   float* __restrict__ h, int N) {
    int wave = threadIdx.x >> 6;
    int lane = threadIdx.x & 63;
    int n = blockIdx.x * 4 + wave;
    if (n >= N) return;
    int off = row_off[n];
    int d = degi[n];
    float4 acc = make_float4(0.f, 0.f, 0.f, 0.f);
    for (int i = 0; i < d; ++i) {
        int2 p = csr[off + i];
        int s = p.x;
        float nr = __int_as_float(p.y);
        float4 v = *(const float4*)&hw[(size_t)s * D_HID + lane * 4];
        acc.x += v.x * nr; acc.y += v.y * nr; acc.z += v.z * nr; acc.w += v.w * nr;
    }
    float di = dinv[n];
    float sl = di * di;
    size_t i4 = (size_t)n * D_HID + lane * 4;
    float4 w  = *(const float4*)&hw[i4];
    float4 hv = *(const float4*)&h[i4];
    float4 bb = *(const float4*)&b[lane * 4];
    float4 r;
    r.x = fmaxf(acc.x + w.x * sl + bb.x, 0.f) + hv.x;
    r.y = fmaxf(acc.y + w.y * sl + bb.y, 0.f) + hv.y;
    r.z = fmaxf(acc.z + w.z * sl + bb.z, 0.f) + hv.z;
    r.w = fmaxf(acc.w + w.w * sl + bb.w, 0.f) + hv.w;
    *(float4*)&h[i4] = r;
}

extern "C" void kernel_launch(void* const* d_in, const int* in_sizes, int n_in,
                              void* d_out, int out_size, void* d_ws, size_t ws_size,
                              hipStream_t stream) {
    const float* x     = (const float*)d_in[0];
    const int*   edge  = (const int*)d_in[1];
    const float* W_emb = (const float*)d_in[2];
    const float* b_emb = (const float*)d_in[3];
    const float* W[3]  = {(const float*)d_in[4], (const float*)d_in[6], (const float*)d_in[8]};
    const float* B[3]  = {(const float*)d_in[5], (const float*)d_in[7], (const float*)d_in[9]};

    int N = in_sizes[0] / 10;       // 100000
    int E = in_sizes[1] / 2;        // 320000
    size_t NH = (size_t)N * D_HID;  // 25.6M elements

    float* h  = (float*)d_out;
    float* hw = (float*)d_ws;                 // NH floats
    int2*  csr = (int2*)(hw + NH);            // E pairs (8B aligned)
    int*   degi    = (int*)(csr + E);
    float* dinv    = (float*)(degi + N);
    int*   row_off = (int*)(dinv + N);
    int*   cursor  = row_off + N;
    int*   partials = cursor + N;             // up to 128 entries

    const int* src = edge;
    const int* dst = edge + E;

    int nb = (N + 1023) / 1024;               // 98 scan blocks

    // ---- CSR build (layer-invariant) ----
    hipMemsetAsync(degi, 0, (size_t)N * sizeof(int), stream);
    deg_kernel<<<(E + 255) / 256, 256, 0, stream>>>(dst, degi, E);
    dinv_kernel<<<(N + 255) / 256, 256, 0, stream>>>(degi, dinv, N);
    scanA<<<nb, 256, 0, stream>>>(degi, row_off, partials, N);
    scanB<<<1, 1, 0, stream>>>(partials, nb);
    scanC<<<nb, 256, 0, stream>>>(row_off, partials, N);
    hipMemsetAsync(cursor, 0, (size_t)N * sizeof(int), stream);
    fill_kernel<<<(E + 255) / 256, 256, 0, stream>>>(src, dst, row_off, cursor, dinv, csr, E);

    // ---- embedding ----
    emb_kernel<<<N, 256, 0, stream>>>(x, W_emb, b_emb, h, N);

    // ---- 3 GCN layers ----
    dim3 ggrid((N + BM - 1) / BM, D_HID / BN);
    for (int l = 0; l < 3; ++l) {
        gemm_fp32<<<ggrid, 256, 0, stream>>>(h, W[l], hw, N);
        agg_combine<<<(N + 3) / 4, 256, 0, stream>>>(row_off, degi, csr, hw, dinv, B[l], h, N);
    }
}

// Round 4
// 513.576 us; speedup vs baseline: 7.9027x; 1.8048x over previous
//
#include <hip/hip_runtime.h>
#include <hip/hip_bf16.h>
#include <stdint.h>

#define D_HID 256

typedef float v4f __attribute__((ext_vector_type(4)));
typedef short v8s __attribute__((ext_vector_type(8)));

#define GLOAD_LDS(g, l) __builtin_amdgcn_global_load_lds( \
    (const __attribute__((address_space(1))) unsigned int*)(g), \
    (__attribute__((address_space(3))) unsigned int*)(l), 16, 0, 0)

static __device__ __forceinline__ unsigned short f2bf(float f) {
    union { float f; uint32_t u; } a; a.f = f;
    uint32_t u = a.u;
    uint32_t r = (u + 0x7FFFu + ((u >> 16) & 1u)) >> 16;   // round-nearest-even
    return (unsigned short)r;
}

// ---------------- degree count ----------------
__global__ void deg_kernel(const int* __restrict__ dst, int* __restrict__ degi, int E) {
    int e = blockIdx.x * blockDim.x + threadIdx.x;
    if (e < E) atomicAdd(&degi[dst[e]], 1);
}

__global__ void dinv_kernel(const int* __restrict__ degi, float* __restrict__ dinv, int N) {
    int n = blockIdx.x * blockDim.x + threadIdx.x;
    if (n < N) dinv[n] = rsqrtf((float)degi[n] + 1.0f);
}

// ---------------- exclusive scan ----------------
__global__ __launch_bounds__(256) void scanA(const int* __restrict__ degi,
                                             int* __restrict__ row_off,
                                             int* __restrict__ partials, int N) {
    __shared__ int sdata[256];
    int tid = threadIdx.x;
    int base = blockIdx.x * 1024 + tid * 4;
    int s[4];
#pragma unroll
    for (int j = 0; j < 4; ++j) s[j] = (base + j < N) ? degi[base + j] : 0;
    int t = s[0] + s[1] + s[2] + s[3];
    sdata[tid] = t;
    __syncthreads();
    for (int ofs = 1; ofs < 256; ofs <<= 1) {
        int v = (tid >= ofs) ? sdata[tid - ofs] : 0;
        __syncthreads();
        sdata[tid] += v;
        __syncthreads();
    }
    int excl = sdata[tid] - t;
    int run = excl;
#pragma unroll
    for (int j = 0; j < 4; ++j) {
        if (base + j < N) row_off[base + j] = run;
        run += s[j];
    }
    if (tid == 255) partials[blockIdx.x] = sdata[255];
}

__global__ void scanB(int* __restrict__ partials, int nb) {
    if (threadIdx.x == 0 && blockIdx.x == 0) {
        int run = 0;
        for (int i = 0; i < nb; ++i) { int t = partials[i]; partials[i] = run; run += t; }
    }
}

__global__ __launch_bounds__(256) void scanC(int* __restrict__ row_off,
                                             const int* __restrict__ partials, int N) {
    int add = partials[blockIdx.x];
    int base = blockIdx.x * 1024 + threadIdx.x * 4;
#pragma unroll
    for (int j = 0; j < 4; ++j)
        if (base + j < N) row_off[base + j] += add;
}

// ---------------- CSR fill ----------------
__global__ void fill_kernel(const int* __restrict__ src, const int* __restrict__ dst,
                            const int* __restrict__ row_off, int* __restrict__ cursor,
                            const float* __restrict__ dinv, int2* __restrict__ csr, int E) {
    int e = blockIdx.x * blockDim.x + threadIdx.x;
    if (e >= E) return;
    int s = src[e], t = dst[e];
    int pos = row_off[t] + atomicAdd(&cursor[t], 1);
    csr[pos] = make_int2(s, __float_as_int(dinv[s] * dinv[t]));
}

// ---------------- weight transpose + bf16 cast: Wt[n][k] = bf16(W[k][n]) ----------------
__global__ __launch_bounds__(256) void transpose_cast(const float* __restrict__ W,
                                                      unsigned short* __restrict__ Wt) {
    __shared__ float t[16][17];
    int bx = blockIdx.x & 15, by = blockIdx.x >> 4;
    int tx = threadIdx.x & 15, ty = threadIdx.x >> 4;
    t[ty][tx] = W[(by * 16 + ty) * 256 + bx * 16 + tx];
    __syncthreads();
    Wt[(size_t)(bx * 16 + ty) * 256 + by * 16 + tx] = f2bf(t[tx][ty]);
}

// ---------------- embedding: h = x @ W_emb + b_emb (K=10); also hb=bf16(h) ----------------
__global__ __launch_bounds__(256) void emb_kernel(const float* __restrict__ x,
                                                  const float* __restrict__ W,
                                                  const float* __restrict__ b,
                                                  float* __restrict__ h,
                                                  unsigned short* __restrict__ hb, int N) {
    int n = blockIdx.x;
    __shared__ float xs[10];
    if (threadIdx.x < 10) xs[threadIdx.x] = x[n * 10 + threadIdx.x];
    __syncthreads();
    int d = threadIdx.x;
    float s = b[d];
#pragma unroll
    for (int k = 0; k < 10; ++k) s += xs[k] * W[k * D_HID + d];
    size_t idx = (size_t)n * D_HID + d;
    h[idx] = s;
    hb[idx] = f2bf(s);
}

// ---------------- bf16 MFMA GEMM: hw[M,256] = hb[M,256] @ W[256,256] ----------------
// A tile 128x32 bf16, B tile (full N) 256x32 bf16, double buffered, global_load_lds.
#define GBM 128
__global__ __launch_bounds__(256) void gemm_bf16(const unsigned short* __restrict__ hb,
                                                 const unsigned short* __restrict__ Wt,
                                                 float* __restrict__ hw, int M) {
    __shared__ unsigned short lds[2 * 12288];   // 48 KB: per buf [A 128*32][B 256*32]
    int tid = threadIdx.x;
    int w = tid >> 6, lane = tid & 63;
    int bm = blockIdx.x * GBM;
    int wr = w >> 1, wc = w & 1;

    v4f acc[4][8] = {};

    const char* hbB = (const char*)hb;
    const char* WtB = (const char*)Wt;

    auto stage = [&](int buf, int k0) {
        unsigned short* Abase = lds + buf * 12288;
        unsigned short* Bbase = Abase + 4096;
#pragma unroll
        for (int r = 0; r < 2; ++r) {                       // A: 8 KB
            int p = r * 4096 + w * 1024 + lane * 16;        // byte offset in tile
            int row = p >> 6, colb = p & 63;
            const char* g = hbB + ((size_t)(bm + row) << 9) + k0 * 2 + colb;
            GLOAD_LDS(g, Abase + (p >> 1) - lane * 8);      // wave-uniform base (lane*16B auto)
        }
#pragma unroll
        for (int r = 0; r < 4; ++r) {                       // B: 16 KB
            int p = r * 4096 + w * 1024 + lane * 16;
            int row = p >> 6, colb = p & 63;
            const char* g = WtB + (row << 9) + k0 * 2 + colb;
            GLOAD_LDS(g, Bbase + (p >> 1) - lane * 8);
        }
    };

    auto compute = [&](int buf) {
        const unsigned short* Abase = lds + buf * 12288;
        const unsigned short* Bbase = Abase + 4096;
        v8s a[4], b[8];
#pragma unroll
        for (int m = 0; m < 4; ++m) {
            int row = wr * 64 + m * 16 + (lane & 15);
            a[m] = *(const v8s*)(Abase + row * 32 + (lane >> 4) * 8);
        }
#pragma unroll
        for (int n = 0; n < 8; ++n) {
            int row = wc * 128 + n * 16 + (lane & 15);
            b[n] = *(const v8s*)(Bbase + row * 32 + (lane >> 4) * 8);
        }
#pragma unroll
        for (int m = 0; m < 4; ++m)
#pragma unroll
            for (int n = 0; n < 8; ++n)
                acc[m][n] = __builtin_amdgcn_mfma_f32_16x16x32_bf16(a[m], b[n], acc[m][n], 0, 0, 0);
    };

    stage(0, 0);
    __syncthreads();
#pragma unroll
    for (int t = 0; t < 7; ++t) {
        stage((t + 1) & 1, (t + 1) * 32);
        compute(t & 1);
        __syncthreads();
    }
    compute(1);

#pragma unroll
    for (int m = 0; m < 4; ++m) {
        int rbase = bm + wr * 64 + m * 16 + (lane >> 4) * 4;
#pragma unroll
        for (int n = 0; n < 8; ++n) {
            int col = wc * 128 + n * 16 + (lane & 15);
#pragma unroll
            for (int q = 0; q < 4; ++q) {
                int row = rbase + q;
                if (row < M) hw[(size_t)row * 256 + col] = acc[m][n][q];
            }
        }
    }
}

// ---------------- fused gather-aggregate + combine; writes h (fp32) and hb (bf16) ----------------
__global__ __launch_bounds__(256) void agg_combine(const int* __restrict__ row_off,
                                                   const int* __restrict__ degi,
                                                   const int2* __restrict__ csr,
                                                   const float* __restrict__ hw,
                                                   const float* __restrict__ dinv,
                                                   const float* __restrict__ b,
                                                   float* __restrict__ h,
                                                   unsigned short* __restrict__ hb, int N) {
    int wave = threadIdx.x >> 6;
    int lane = threadIdx.x & 63;
    int n = blockIdx.x * 4 + wave;
    if (n >= N) return;
    int off = row_off[n];
    int d = degi[n];
    float4 acc = make_float4(0.f, 0.f, 0.f, 0.f);
    for (int i = 0; i < d; ++i) {
        int2 p = csr[off + i];
        float nr = __int_as_float(p.y);
        float4 v = *(const float4*)&hw[(size_t)p.x * D_HID + lane * 4];
        acc.x += v.x * nr; acc.y += v.y * nr; acc.z += v.z * nr; acc.w += v.w * nr;
    }
    float di = dinv[n];
    float sl = di * di;
    size_t i4 = (size_t)n * D_HID + lane * 4;
    float4 wv = *(const float4*)&hw[i4];
    float4 hv = *(const float4*)&h[i4];
    float4 bb = *(const float4*)&b[lane * 4];
    float4 r;
    r.x = fmaxf(acc.x + wv.x * sl + bb.x, 0.f) + hv.x;
    r.y = fmaxf(acc.y + wv.y * sl + bb.y, 0.f) + hv.y;
    r.z = fmaxf(acc.z + wv.z * sl + bb.z, 0.f) + hv.z;
    r.w = fmaxf(acc.w + wv.w * sl + bb.w, 0.f) + hv.w;
    *(float4*)&h[i4] = r;
    ushort4 o;
    o.x = f2bf(r.x); o.y = f2bf(r.y); o.z = f2bf(r.z); o.w = f2bf(r.w);
    *(ushort4*)&hb[i4] = o;
}

extern "C" void kernel_launch(void* const* d_in, const int* in_sizes, int n_in,
                              void* d_out, int out_size, void* d_ws, size_t ws_size,
                              hipStream_t stream) {
    const float* x     = (const float*)d_in[0];
    const int*   edge  = (const int*)d_in[1];
    const float* W_emb = (const float*)d_in[2];
    const float* b_emb = (const float*)d_in[3];
    const float* W[3]  = {(const float*)d_in[4], (const float*)d_in[6], (const float*)d_in[8]};
    const float* B[3]  = {(const float*)d_in[5], (const float*)d_in[7], (const float*)d_in[9]};

    int N = in_sizes[0] / 10;       // 100000
    int E = in_sizes[1] / 2;        // 320000
    size_t NH = (size_t)N * D_HID;
    int Mpad = ((N + GBM - 1) / GBM) * GBM;     // 100096

    float* h  = (float*)d_out;
    float* hw = (float*)d_ws;                           // NH floats
    unsigned short* hb = (unsigned short*)(hw + NH);    // Mpad*256
    unsigned short* Wt = hb + (size_t)Mpad * D_HID;     // 3*65536
    int2*  csr = (int2*)(Wt + 3 * 65536);               // E
    int*   degi     = (int*)(csr + E);
    float* dinv     = (float*)(degi + N);
    int*   row_off  = (int*)(dinv + N);
    int*   cursor   = row_off + N;
    int*   partials = cursor + N;

    const int* src = edge;
    const int* dst = edge + E;

    int nb = (N + 1023) / 1024;

    // ---- CSR build (layer-invariant) ----
    hipMemsetAsync(degi, 0, (size_t)N * sizeof(int), stream);
    deg_kernel<<<(E + 255) / 256, 256, 0, stream>>>(dst, degi, E);
    dinv_kernel<<<(N + 255) / 256, 256, 0, stream>>>(degi, dinv, N);
    scanA<<<nb, 256, 0, stream>>>(degi, row_off, partials, N);
    scanB<<<1, 1, 0, stream>>>(partials, nb);
    scanC<<<nb, 256, 0, stream>>>(row_off, partials, N);
    hipMemsetAsync(cursor, 0, (size_t)N * sizeof(int), stream);
    fill_kernel<<<(E + 255) / 256, 256, 0, stream>>>(src, dst, row_off, cursor, dinv, csr, E);

    // ---- weights -> bf16 transposed ----
    for (int l = 0; l < 3; ++l)
        transpose_cast<<<256, 256, 0, stream>>>(W[l], Wt + (size_t)l * 65536);

    // ---- embedding ----
    emb_kernel<<<N, 256, 0, stream>>>(x, W_emb, b_emb, h, hb, N);

    // ---- 3 GCN layers ----
    int gblocks = (N + GBM - 1) / GBM;
    for (int l = 0; l < 3; ++l) {
        gemm_bf16<<<gblocks, 256, 0, stream>>>(hb, Wt + (size_t)l * 65536, hw, N);
        agg_combine<<<(N + 3) / 4, 256, 0, stream>>>(row_off, degi, csr, hw, dinv, B[l], h, hb, N);
    }
}

// Round 6
// 410.928 us; speedup vs baseline: 9.8768x; 1.2498x over previous
//
#include <hip/hip_runtime.h>
#include <hip/hip_bf16.h>
#include <stdint.h>

#define D_HID 256

typedef float v4f __attribute__((ext_vector_type(4)));
typedef short v8s __attribute__((ext_vector_type(8)));

#define GLOAD_LDS(g, l) __builtin_amdgcn_global_load_lds( \
    (const __attribute__((address_space(1))) unsigned int*)(g), \
    (__attribute__((address_space(3))) unsigned int*)(l), 16, 0, 0)

static __device__ __forceinline__ unsigned short f2bf(float f) {
    union { float f; uint32_t u; } a; a.f = f;
    uint32_t u = a.u;
    uint32_t r = (u + 0x7FFFu + ((u >> 16) & 1u)) >> 16;   // round-nearest-even
    return (unsigned short)r;
}
static __device__ __forceinline__ float bf2f(unsigned short u) {
    union { uint32_t u; float f; } a; a.u = ((uint32_t)u) << 16;
    return a.f;
}

// ---------------- degree count ----------------
__global__ void deg_kernel(const int* __restrict__ dst, int* __restrict__ degi, int E) {
    int e = blockIdx.x * blockDim.x + threadIdx.x;
    if (e < E) atomicAdd(&degi[dst[e]], 1);
}

__global__ void dinv_kernel(const int* __restrict__ degi, float* __restrict__ dinv, int N) {
    int n = blockIdx.x * blockDim.x + threadIdx.x;
    if (n < N) dinv[n] = rsqrtf((float)degi[n] + 1.0f);
}

// ---------------- exclusive scan ----------------
__global__ __launch_bounds__(256) void scanA(const int* __restrict__ degi,
                                             int* __restrict__ row_off,
                                             int* __restrict__ partials, int N) {
    __shared__ int sdata[256];
    int tid = threadIdx.x;
    int base = blockIdx.x * 1024 + tid * 4;
    int s[4];
#pragma unroll
    for (int j = 0; j < 4; ++j) s[j] = (base + j < N) ? degi[base + j] : 0;
    int t = s[0] + s[1] + s[2] + s[3];
    sdata[tid] = t;
    __syncthreads();
    for (int ofs = 1; ofs < 256; ofs <<= 1) {
        int v = (tid >= ofs) ? sdata[tid - ofs] : 0;
        __syncthreads();
        sdata[tid] += v;
        __syncthreads();
    }
    int excl = sdata[tid] - t;
    int run = excl;
#pragma unroll
    for (int j = 0; j < 4; ++j) {
        if (base + j < N) row_off[base + j] = run;
        run += s[j];
    }
    if (tid == 255) partials[blockIdx.x] = sdata[255];
}

// parallel scan of <=128 partials
__global__ __launch_bounds__(128) void scanB(int* __restrict__ partials, int nb) {
    __shared__ int s[128];
    int tid = threadIdx.x;
    int v = (tid < nb) ? partials[tid] : 0;
    s[tid] = v;
    __syncthreads();
    for (int ofs = 1; ofs < 128; ofs <<= 1) {
        int t = (tid >= ofs) ? s[tid - ofs] : 0;
        __syncthreads();
        s[tid] += t;
        __syncthreads();
    }
    if (tid < nb) partials[tid] = s[tid] - v;   // exclusive
}

__global__ __launch_bounds__(256) void scanC(int* __restrict__ row_off,
                                             const int* __restrict__ partials, int N) {
    int add = partials[blockIdx.x];
    int base = blockIdx.x * 1024 + threadIdx.x * 4;
#pragma unroll
    for (int j = 0; j < 4; ++j)
        if (base + j < N) row_off[base + j] += add;
}

// ---------------- CSR fill ----------------
__global__ void fill_kernel(const int* __restrict__ src, const int* __restrict__ dst,
                            const int* __restrict__ row_off, int* __restrict__ cursor,
                            const float* __restrict__ dinv, int2* __restrict__ csr, int E) {
    int e = blockIdx.x * blockDim.x + threadIdx.x;
    if (e >= E) return;
    int s = src[e], t = dst[e];
    int pos = row_off[t] + atomicAdd(&cursor[t], 1);
    csr[pos] = make_int2(s, __float_as_int(dinv[s] * dinv[t]));
}

// ---------------- weight transpose + bf16 cast: Wt[n][k] = bf16(W[k][n]) ----------------
__global__ __launch_bounds__(256) void transpose_cast(const float* __restrict__ W,
                                                      unsigned short* __restrict__ Wt) {
    __shared__ float t[16][17];
    int bx = blockIdx.x & 15, by = blockIdx.x >> 4;
    int tx = threadIdx.x & 15, ty = threadIdx.x >> 4;
    t[ty][tx] = W[(by * 16 + ty) * 256 + bx * 16 + tx];
    __syncthreads();
    Wt[(size_t)(bx * 16 + ty) * 256 + by * 16 + tx] = f2bf(t[tx][ty]);
}

// ---------------- embedding: h = x @ W_emb + b_emb (K=10); also hb=bf16(h) ----------------
__global__ __launch_bounds__(256) void emb_kernel(const float* __restrict__ x,
                                                  const float* __restrict__ W,
                                                  const float* __restrict__ b,
                                                  float* __restrict__ h,
                                                  unsigned short* __restrict__ hb, int N) {
    int wave = threadIdx.x >> 6;
    int lane = threadIdx.x & 63;
    int n = blockIdx.x * 4 + wave;
    if (n >= N) return;
    float xv = (lane < 10) ? x[n * 10 + lane] : 0.f;
    float s0 = b[lane * 4 + 0], s1 = b[lane * 4 + 1], s2 = b[lane * 4 + 2], s3 = b[lane * 4 + 3];
#pragma unroll
    for (int k = 0; k < 10; ++k) {
        float xk = __shfl(xv, k);
        s0 += xk * W[k * D_HID + lane * 4 + 0];
        s1 += xk * W[k * D_HID + lane * 4 + 1];
        s2 += xk * W[k * D_HID + lane * 4 + 2];
        s3 += xk * W[k * D_HID + lane * 4 + 3];
    }
    size_t i4 = (size_t)n * D_HID + lane * 4;
    float4 r = make_float4(s0, s1, s2, s3);
    *(float4*)&h[i4] = r;
    ushort4 o; o.x = f2bf(s0); o.y = f2bf(s1); o.z = f2bf(s2); o.w = f2bf(s3);
    *(ushort4*)&hb[i4] = o;
}

// ---------------- bf16 MFMA GEMM: hwb[M,256](bf16) = hb[M,256] @ W[256,256] ----------------
#define GBM 128
__global__ __launch_bounds__(256) void gemm_bf16(const unsigned short* __restrict__ hb,
                                                 const unsigned short* __restrict__ Wt,
                                                 unsigned short* __restrict__ hwb, int M) {
    __shared__ unsigned short lds[2 * 12288];   // 48 KB: per buf [A 128*32][B 256*32]
    int tid = threadIdx.x;
    int w = tid >> 6, lane = tid & 63;
    int bm = blockIdx.x * GBM;
    int wr = w >> 1, wc = w & 1;

    v4f acc[4][8] = {};

    const char* hbB = (const char*)hb;
    const char* WtB = (const char*)Wt;

    auto stage = [&](int buf, int k0) {
        unsigned short* Abase = lds + buf * 12288;
        unsigned short* Bbase = Abase + 4096;
#pragma unroll
        for (int r = 0; r < 2; ++r) {                       // A: 8 KB
            int p = r * 4096 + w * 1024 + lane * 16;        // byte offset in tile
            int row = p >> 6, colb = p & 63;
            const char* g = hbB + ((size_t)(bm + row) << 9) + k0 * 2 + colb;
            GLOAD_LDS(g, Abase + (p >> 1) - lane * 8);      // wave-uniform base (lane*16B auto)
        }
#pragma unroll
        for (int r = 0; r < 4; ++r) {                       // B: 16 KB
            int p = r * 4096 + w * 1024 + lane * 16;
            int row = p >> 6, colb = p & 63;
            const char* g = WtB + (row << 9) + k0 * 2 + colb;
            GLOAD_LDS(g, Bbase + (p >> 1) - lane * 8);
        }
    };

    auto compute = [&](int buf) {
        const unsigned short* Abase = lds + buf * 12288;
        const unsigned short* Bbase = Abase + 4096;
        v8s a[4], b[8];
#pragma unroll
        for (int m = 0; m < 4; ++m) {
            int row = wr * 64 + m * 16 + (lane & 15);
            a[m] = *(const v8s*)(Abase + row * 32 + (lane >> 4) * 8);
        }
#pragma unroll
        for (int n = 0; n < 8; ++n) {
            int row = wc * 128 + n * 16 + (lane & 15);
            b[n] = *(const v8s*)(Bbase + row * 32 + (lane >> 4) * 8);
        }
#pragma unroll
        for (int m = 0; m < 4; ++m)
#pragma unroll
            for (int n = 0; n < 8; ++n)
                acc[m][n] = __builtin_amdgcn_mfma_f32_16x16x32_bf16(a[m], b[n], acc[m][n], 0, 0, 0);
    };

    stage(0, 0);
    __syncthreads();
#pragma unroll
    for (int t = 0; t < 7; ++t) {
        stage((t + 1) & 1, (t + 1) * 32);
        compute(t & 1);
        __syncthreads();
    }
    compute(1);

#pragma unroll
    for (int m = 0; m < 4; ++m) {
        int rbase = bm + wr * 64 + m * 16 + (lane >> 4) * 4;
#pragma unroll
        for (int n = 0; n < 8; ++n) {
            int col = wc * 128 + n * 16 + (lane & 15);
#pragma unroll
            for (int q = 0; q < 4; ++q) {
                int row = rbase + q;
                if (row < M) hwb[(size_t)row * 256 + col] = f2bf(acc[m][n][q]);
            }
        }
    }
}

// ---------------- fused gather-aggregate + combine (bf16 hw) ----------------
__global__ __launch_bounds__(256) void agg_combine(const int* __restrict__ row_off,
                                                   const int* __restrict__ degi,
                                                   const int2* __restrict__ csr,
                                                   const unsigned short* __restrict__ hwb,
                                                   const float* __restrict__ dinv,
                                                   const float* __restrict__ b,
                                                   float* __restrict__ h,
                                                   unsigned short* __restrict__ hb,
                                                   int N, int write_hb) {
    int wave = threadIdx.x >> 6;
    int lane = threadIdx.x & 63;
    int n = blockIdx.x * 4 + wave;
    if (n >= N) return;
    int off = row_off[n];
    int d = degi[n];
    float4 acc = make_float4(0.f, 0.f, 0.f, 0.f);
    int2 p = (d > 0) ? csr[off] : make_int2(0, 0);
    for (int i = 0; i < d; ++i) {
        int2 pn = (i + 1 < d) ? csr[off + i + 1] : p;   // prefetch next edge
        float nr = __int_as_float(p.y);
        ushort4 rv = *(const ushort4*)&hwb[(size_t)p.x * D_HID + lane * 4];
        acc.x += bf2f(rv.x) * nr;
        acc.y += bf2f(rv.y) * nr;
        acc.z += bf2f(rv.z) * nr;
        acc.w += bf2f(rv.w) * nr;
        p = pn;
    }
    float di = dinv[n];
    float sl = di * di;
    size_t i4 = (size_t)n * D_HID + lane * 4;
    ushort4 wv4 = *(const ushort4*)&hwb[i4];
    float4 hv = *(const float4*)&h[i4];
    float4 bb = *(const float4*)&b[lane * 4];
    float4 r;
    r.x = fmaxf(acc.x + bf2f(wv4.x) * sl + bb.x, 0.f) + hv.x;
    r.y = fmaxf(acc.y + bf2f(wv4.y) * sl + bb.y, 0.f) + hv.y;
    r.z = fmaxf(acc.z + bf2f(wv4.z) * sl + bb.z, 0.f) + hv.z;
    r.w = fmaxf(acc.w + bf2f(wv4.w) * sl + bb.w, 0.f) + hv.w;
    *(float4*)&h[i4] = r;
    if (write_hb) {
        ushort4 o;
        o.x = f2bf(r.x); o.y = f2bf(r.y); o.z = f2bf(r.z); o.w = f2bf(r.w);
        *(ushort4*)&hb[i4] = o;
    }
}

extern "C" void kernel_launch(void* const* d_in, const int* in_sizes, int n_in,
                              void* d_out, int out_size, void* d_ws, size_t ws_size,
                              hipStream_t stream) {
    const float* x     = (const float*)d_in[0];
    const int*   edge  = (const int*)d_in[1];
    const float* W_emb = (const float*)d_in[2];
    const float* b_emb = (const float*)d_in[3];
    const float* W[3]  = {(const float*)d_in[4], (const float*)d_in[6], (const float*)d_in[8]};
    const float* B[3]  = {(const float*)d_in[5], (const float*)d_in[7], (const float*)d_in[9]};

    int N = in_sizes[0] / 10;       // 100000
    int E = in_sizes[1] / 2;        // 320000
    size_t NH = (size_t)N * D_HID;
    int Mpad = ((N + GBM - 1) / GBM) * GBM;     // 100096

    float* h = (float*)d_out;
    unsigned short* hwb = (unsigned short*)d_ws;        // NH bf16
    unsigned short* hb  = hwb + NH;                     // Mpad*256 bf16
    unsigned short* Wt  = hb + (size_t)Mpad * D_HID;    // 3*65536 bf16
    int2*  csr = (int2*)(Wt + 3 * 65536);               // E
    int*   degi     = (int*)(csr + E);
    float* dinv     = (float*)(degi + N);
    int*   row_off  = (int*)(dinv + N);
    int*   cursor   = row_off + N;
    int*   partials = cursor + N;

    const int* src = edge;
    const int* dst = edge + E;

    int nb = (N + 1023) / 1024;     // 98

    // ---- CSR build (layer-invariant) ----
    hipMemsetAsync(degi, 0, (size_t)N * sizeof(int), stream);
    deg_kernel<<<(E + 255) / 256, 256, 0, stream>>>(dst, degi, E);
    dinv_kernel<<<(N + 255) / 256, 256, 0, stream>>>(degi, dinv, N);
    scanA<<<nb, 256, 0, stream>>>(degi, row_off, partials, N);
    scanB<<<1, 128, 0, stream>>>(partials, nb);
    scanC<<<nb, 256, 0, stream>>>(row_off, partials, N);
    hipMemsetAsync(cursor, 0, (size_t)N * sizeof(int), stream);
    fill_kernel<<<(E + 255) / 256, 256, 0, stream>>>(src, dst, row_off, cursor, dinv, csr, E);

    // ---- weights -> bf16 transposed ----
    for (int l = 0; l < 3; ++l)
        transpose_cast<<<256, 256, 0, stream>>>(W[l], Wt + (size_t)l * 65536);

    // ---- embedding ----
    emb_kernel<<<(N + 3) / 4, 256, 0, stream>>>(x, W_emb, b_emb, h, hb, N);

    // ---- 3 GCN layers ----
    int gblocks = (N + GBM - 1) / GBM;
    for (int l = 0; l < 3; ++l) {
        gemm_bf16<<<gblocks, 256, 0, stream>>>(hb, Wt + (size_t)l * 65536, hwb, N);
        agg_combine<<<(N + 3) / 4, 256, 0, stream>>>(row_off, degi, csr, hwb, dinv, B[l],
                                                     h, hb, N, l < 2 ? 1 : 0);
    }
}

// Round 7
// 327.781 us; speedup vs baseline: 12.3822x; 1.2537x over previous
//
#include <hip/hip_runtime.h>
#include <hip/hip_bf16.h>
#include <stdint.h>

#define D_HID 256

typedef float v4f __attribute__((ext_vector_type(4)));
typedef short v8s __attribute__((ext_vector_type(8)));

#define GLOAD_LDS(g, l) __builtin_amdgcn_global_load_lds( \
    (const __attribute__((address_space(1))) unsigned int*)(g), \
    (__attribute__((address_space(3))) unsigned int*)(l), 16, 0, 0)

static __device__ __forceinline__ unsigned short f2bf(float f) {
    union { float f; uint32_t u; } a; a.f = f;
    uint32_t u = a.u;
    uint32_t r = (u + 0x7FFFu + ((u >> 16) & 1u)) >> 16;   // round-nearest-even
    return (unsigned short)r;
}
static __device__ __forceinline__ float bf2f(unsigned short u) {
    union { uint32_t u; float f; } a; a.u = ((uint32_t)u) << 16;
    return a.f;
}

// ---------------- degree count ----------------
__global__ void deg_kernel(const int* __restrict__ dst, int* __restrict__ degi, int E) {
    int e = blockIdx.x * blockDim.x + threadIdx.x;
    if (e < E) atomicAdd(&degi[dst[e]], 1);
}

__global__ void dinv_kernel(const int* __restrict__ degi, float* __restrict__ dinv, int N) {
    int n = blockIdx.x * blockDim.x + threadIdx.x;
    if (n < N) dinv[n] = rsqrtf((float)degi[n] + 1.0f);
}

// ---------------- exclusive scan ----------------
__global__ __launch_bounds__(256) void scanA(const int* __restrict__ degi,
                                             int* __restrict__ row_off,
                                             int* __restrict__ partials, int N) {
    __shared__ int sdata[256];
    int tid = threadIdx.x;
    int base = blockIdx.x * 1024 + tid * 4;
    int s[4];
#pragma unroll
    for (int j = 0; j < 4; ++j) s[j] = (base + j < N) ? degi[base + j] : 0;
    int t = s[0] + s[1] + s[2] + s[3];
    sdata[tid] = t;
    __syncthreads();
    for (int ofs = 1; ofs < 256; ofs <<= 1) {
        int v = (tid >= ofs) ? sdata[tid - ofs] : 0;
        __syncthreads();
        sdata[tid] += v;
        __syncthreads();
    }
    int excl = sdata[tid] - t;
    int run = excl;
#pragma unroll
    for (int j = 0; j < 4; ++j) {
        if (base + j < N) row_off[base + j] = run;
        run += s[j];
    }
    if (tid == 255) partials[blockIdx.x] = sdata[255];
}

__global__ __launch_bounds__(128) void scanB(int* __restrict__ partials, int nb) {
    __shared__ int s[128];
    int tid = threadIdx.x;
    int v = (tid < nb) ? partials[tid] : 0;
    s[tid] = v;
    __syncthreads();
    for (int ofs = 1; ofs < 128; ofs <<= 1) {
        int t = (tid >= ofs) ? s[tid - ofs] : 0;
        __syncthreads();
        s[tid] += t;
        __syncthreads();
    }
    if (tid < nb) partials[tid] = s[tid] - v;   // exclusive
}

__global__ __launch_bounds__(256) void scanC(int* __restrict__ row_off,
                                             const int* __restrict__ partials, int N) {
    int add = partials[blockIdx.x];
    int base = blockIdx.x * 1024 + threadIdx.x * 4;
#pragma unroll
    for (int j = 0; j < 4; ++j)
        if (base + j < N) row_off[base + j] += add;
}

// ---------------- CSR fill ----------------
__global__ void fill_kernel(const int* __restrict__ src, const int* __restrict__ dst,
                            const int* __restrict__ row_off, int* __restrict__ cursor,
                            const float* __restrict__ dinv, int2* __restrict__ csr, int E) {
    int e = blockIdx.x * blockDim.x + threadIdx.x;
    if (e >= E) return;
    int s = src[e], t = dst[e];
    int pos = row_off[t] + atomicAdd(&cursor[t], 1);
    csr[pos] = make_int2(s, __float_as_int(dinv[s] * dinv[t]));
}

// ---------------- weight transpose + bf16 cast: Wt[n][k] = bf16(W[k][n]) ----------------
__global__ __launch_bounds__(256) void transpose_cast(const float* __restrict__ W,
                                                      unsigned short* __restrict__ Wt) {
    __shared__ float t[16][17];
    int bx = blockIdx.x & 15, by = blockIdx.x >> 4;
    int tx = threadIdx.x & 15, ty = threadIdx.x >> 4;
    t[ty][tx] = W[(by * 16 + ty) * 256 + bx * 16 + tx];
    __syncthreads();
    Wt[(size_t)(bx * 16 + ty) * 256 + by * 16 + tx] = f2bf(t[tx][ty]);
}

// ---------------- embedding: hb = bf16(x @ W_emb + b_emb)  (K=10) ----------------
__global__ __launch_bounds__(256) void emb_kernel(const float* __restrict__ x,
                                                  const float* __restrict__ W,
                                                  const float* __restrict__ b,
                                                  unsigned short* __restrict__ hb, int N) {
    int wave = threadIdx.x >> 6;
    int lane = threadIdx.x & 63;
    int n = blockIdx.x * 4 + wave;
    if (n >= N) return;
    float xv = (lane < 10) ? x[n * 10 + lane] : 0.f;
    float s0 = b[lane * 4 + 0], s1 = b[lane * 4 + 1], s2 = b[lane * 4 + 2], s3 = b[lane * 4 + 3];
#pragma unroll
    for (int k = 0; k < 10; ++k) {
        float xk = __shfl(xv, k);
        s0 += xk * W[k * D_HID + lane * 4 + 0];
        s1 += xk * W[k * D_HID + lane * 4 + 1];
        s2 += xk * W[k * D_HID + lane * 4 + 2];
        s3 += xk * W[k * D_HID + lane * 4 + 3];
    }
    size_t i4 = (size_t)n * D_HID + lane * 4;
    ushort4 o; o.x = f2bf(s0); o.y = f2bf(s1); o.z = f2bf(s2); o.w = f2bf(s3);
    *(ushort4*)&hb[i4] = o;
}

// ---------------- bf16 MFMA GEMM: hwb[M,256](bf16) = hb[M,256] @ W[256,256] ----------------
#define GBM 128
__global__ __launch_bounds__(256) void gemm_bf16(const unsigned short* __restrict__ hb,
                                                 const unsigned short* __restrict__ Wt,
                                                 unsigned short* __restrict__ hwb, int M) {
    __shared__ unsigned short lds[2 * 12288];   // 48 KB: per buf [A 128*32][B 256*32]
    int tid = threadIdx.x;
    int w = tid >> 6, lane = tid & 63;
    int bm = blockIdx.x * GBM;
    int wr = w >> 1, wc = w & 1;

    v4f acc[4][8] = {};

    const char* hbB = (const char*)hb;
    const char* WtB = (const char*)Wt;

    auto stage = [&](int buf, int k0) {
        unsigned short* Abase = lds + buf * 12288;
        unsigned short* Bbase = Abase + 4096;
#pragma unroll
        for (int r = 0; r < 2; ++r) {                       // A: 8 KB
            int p = r * 4096 + w * 1024 + lane * 16;        // byte offset in tile
            int row = p >> 6, colb = p & 63;
            const char* g = hbB + ((size_t)(bm + row) << 9) + k0 * 2 + colb;
            GLOAD_LDS(g, Abase + (p >> 1) - lane * 8);      // wave-uniform base (lane*16B auto)
        }
#pragma unroll
        for (int r = 0; r < 4; ++r) {                       // B: 16 KB
            int p = r * 4096 + w * 1024 + lane * 16;
            int row = p >> 6, colb = p & 63;
            const char* g = WtB + (row << 9) + k0 * 2 + colb;
            GLOAD_LDS(g, Bbase + (p >> 1) - lane * 8);
        }
    };

    auto compute = [&](int buf) {
        const unsigned short* Abase = lds + buf * 12288;
        const unsigned short* Bbase = Abase + 4096;
        v8s a[4], b[8];
#pragma unroll
        for (int m = 0; m < 4; ++m) {
            int row = wr * 64 + m * 16 + (lane & 15);
            a[m] = *(const v8s*)(Abase + row * 32 + (lane >> 4) * 8);
        }
#pragma unroll
        for (int n = 0; n < 8; ++n) {
            int row = wc * 128 + n * 16 + (lane & 15);
            b[n] = *(const v8s*)(Bbase + row * 32 + (lane >> 4) * 8);
        }
#pragma unroll
        for (int m = 0; m < 4; ++m)
#pragma unroll
            for (int n = 0; n < 8; ++n)
                acc[m][n] = __builtin_amdgcn_mfma_f32_16x16x32_bf16(a[m], b[n], acc[m][n], 0, 0, 0);
    };

    stage(0, 0);
    __syncthreads();
#pragma unroll
    for (int t = 0; t < 7; ++t) {
        stage((t + 1) & 1, (t + 1) * 32);
        compute(t & 1);
        __syncthreads();
    }
    compute(1);

#pragma unroll
    for (int m = 0; m < 4; ++m) {
        int rbase = bm + wr * 64 + m * 16 + (lane >> 4) * 4;
#pragma unroll
        for (int n = 0; n < 8; ++n) {
            int col = wc * 128 + n * 16 + (lane & 15);
#pragma unroll
            for (int q = 0; q < 4; ++q) {
                int row = rbase + q;
                if (row < M) hwb[(size_t)row * 256 + col] = f2bf(acc[m][n][q]);
            }
        }
    }
}

// ---------------- fused gather-aggregate + combine (all-bf16 residual stream) ----------------
// hb_new = bf16( relu(agg + hwb*dinv^2 + b) + hb_old );  last layer: out = fp32(...)
__global__ __launch_bounds__(256) void agg_combine(const int* __restrict__ row_off,
                                                   const int* __restrict__ degi,
                                                   const int2* __restrict__ csr,
                                                   const unsigned short* __restrict__ hwb,
                                                   const float* __restrict__ dinv,
                                                   const float* __restrict__ b,
                                                   unsigned short* __restrict__ hb,
                                                   float* __restrict__ out,
                                                   int N, int last) {
    int wave = threadIdx.x >> 6;
    int lane = threadIdx.x & 63;
    int n = blockIdx.x * 4 + wave;
    if (n >= N) return;
    int off = row_off[n];
    int d = degi[n];
    float4 acc = make_float4(0.f, 0.f, 0.f, 0.f);
    int i = 0;
    for (; i + 2 <= d; i += 2) {            // dual-issue: 2 independent row loads
        int2 p0 = csr[off + i];
        int2 p1 = csr[off + i + 1];
        float n0 = __int_as_float(p0.y);
        float n1 = __int_as_float(p1.y);
        ushort4 r0 = *(const ushort4*)&hwb[(size_t)p0.x * D_HID + lane * 4];
        ushort4 r1 = *(const ushort4*)&hwb[(size_t)p1.x * D_HID + lane * 4];
        acc.x += bf2f(r0.x) * n0 + bf2f(r1.x) * n1;
        acc.y += bf2f(r0.y) * n0 + bf2f(r1.y) * n1;
        acc.z += bf2f(r0.z) * n0 + bf2f(r1.z) * n1;
        acc.w += bf2f(r0.w) * n0 + bf2f(r1.w) * n1;
    }
    if (i < d) {
        int2 p0 = csr[off + i];
        float n0 = __int_as_float(p0.y);
        ushort4 r0 = *(const ushort4*)&hwb[(size_t)p0.x * D_HID + lane * 4];
        acc.x += bf2f(r0.x) * n0;
        acc.y += bf2f(r0.y) * n0;
        acc.z += bf2f(r0.z) * n0;
        acc.w += bf2f(r0.w) * n0;
    }
    float di = dinv[n];
    float sl = di * di;
    size_t i4 = (size_t)n * D_HID + lane * 4;
    ushort4 wv4 = *(const ushort4*)&hwb[i4];
    ushort4 hv4 = *(const ushort4*)&hb[i4];
    float4 bb = *(const float4*)&b[lane * 4];
    float4 r;
    r.x = fmaxf(acc.x + bf2f(wv4.x) * sl + bb.x, 0.f) + bf2f(hv4.x);
    r.y = fmaxf(acc.y + bf2f(wv4.y) * sl + bb.y, 0.f) + bf2f(hv4.y);
    r.z = fmaxf(acc.z + bf2f(wv4.z) * sl + bb.z, 0.f) + bf2f(hv4.z);
    r.w = fmaxf(acc.w + bf2f(wv4.w) * sl + bb.w, 0.f) + bf2f(hv4.w);
    if (last) {
        *(float4*)&out[i4] = r;
    } else {
        ushort4 o;
        o.x = f2bf(r.x); o.y = f2bf(r.y); o.z = f2bf(r.z); o.w = f2bf(r.w);
        *(ushort4*)&hb[i4] = o;
    }
}

extern "C" void kernel_launch(void* const* d_in, const int* in_sizes, int n_in,
                              void* d_out, int out_size, void* d_ws, size_t ws_size,
                              hipStream_t stream) {
    const float* x     = (const float*)d_in[0];
    const int*   edge  = (const int*)d_in[1];
    const float* W_emb = (const float*)d_in[2];
    const float* b_emb = (const float*)d_in[3];
    const float* W[3]  = {(const float*)d_in[4], (const float*)d_in[6], (const float*)d_in[8]};
    const float* B[3]  = {(const float*)d_in[5], (const float*)d_in[7], (const float*)d_in[9]};

    int N = in_sizes[0] / 10;       // 100000
    int E = in_sizes[1] / 2;        // 320000
    size_t NH = (size_t)N * D_HID;
    int Mpad = ((N + GBM - 1) / GBM) * GBM;     // 100096

    float* out = (float*)d_out;
    unsigned short* hwb = (unsigned short*)d_ws;        // NH bf16
    unsigned short* hb  = hwb + NH;                     // Mpad*256 bf16
    unsigned short* Wt  = hb + (size_t)Mpad * D_HID;    // 3*65536 bf16
    int2*  csr = (int2*)(Wt + 3 * 65536);               // E
    int*   degi     = (int*)(csr + E);
    float* dinv     = (float*)(degi + N);
    int*   row_off  = (int*)(dinv + N);
    int*   cursor   = row_off + N;
    int*   partials = cursor + N;

    const int* src = edge;
    const int* dst = edge + E;

    int nb = (N + 1023) / 1024;     // 98

    // ---- CSR build (layer-invariant) ----
    hipMemsetAsync(degi, 0, (size_t)N * sizeof(int), stream);
    deg_kernel<<<(E + 255) / 256, 256, 0, stream>>>(dst, degi, E);
    dinv_kernel<<<(N + 255) / 256, 256, 0, stream>>>(degi, dinv, N);
    scanA<<<nb, 256, 0, stream>>>(degi, row_off, partials, N);
    scanB<<<1, 128, 0, stream>>>(partials, nb);
    scanC<<<nb, 256, 0, stream>>>(row_off, partials, N);
    hipMemsetAsync(cursor, 0, (size_t)N * sizeof(int), stream);
    fill_kernel<<<(E + 255) / 256, 256, 0, stream>>>(src, dst, row_off, cursor, dinv, csr, E);

    // ---- weights -> bf16 transposed ----
    for (int l = 0; l < 3; ++l)
        transpose_cast<<<256, 256, 0, stream>>>(W[l], Wt + (size_t)l * 65536);

    // ---- embedding ----
    emb_kernel<<<(N + 3) / 4, 256, 0, stream>>>(x, W_emb, b_emb, hb, N);

    // ---- 3 GCN layers ----
    int gblocks = (N + GBM - 1) / GBM;
    for (int l = 0; l < 3; ++l) {
        gemm_bf16<<<gblocks, 256, 0, stream>>>(hb, Wt + (size_t)l * 65536, hwb, N);
        agg_combine<<<(N + 3) / 4, 256, 0, stream>>>(row_off, degi, csr, hwb, dinv, B[l],
                                                     hb, out, N, l == 2 ? 1 : 0);
    }
}